// Round 6
// baseline (279.764 us; speedup 1.0000x reference)
//
#include <hip/hip_runtime.h>
#include <hip/hip_cooperative_groups.h>
#include <math.h>

namespace cg = cooperative_groups;

#define IMG   512
#define NIMG  24
#define XST   72     // X stride (halfs): rows 16B-aligned
#define TST   104    // T' stride (row length 96)
#define RST   56     // R stride (row length 48)
#define UST   88     // U' stride (row length 80)

// ---- LDS pool layout (units: halfs), 32x64 output tile ----
#define SA_TL  0        // 48*104 = 4992
#define SA_TH  4992     // 4992
#define SA_X   9984     // 96*72 = 6912 (dead after A)
#define SA_R   9984     // 3 x 80*56 = 13440 -> [9984, 23424)
#define RSZ    4480
#define SA_U   0        // 3 x 32*88 -> [0, 8448)
#define USZ    2816
#define SA_FT  22112    // 4 modes x 41 starts x 8 = 1312 -> [22112, 23424)
#define POOLSZ 23424    // 46848 B -> 3 blocks/CU

typedef _Float16 v8h __attribute__((ext_vector_type(8)));
typedef float    v4f __attribute__((ext_vector_type(4)));

__device__ __forceinline__ v8h load8(const _Float16* p) {
    union { uint4 u; v8h h; } c;
    c.u = *(const uint4*)p;
    return c.h;
}

__device__ __forceinline__ unsigned pkrtz(float a, float b) {
    union { __fp16 __attribute__((ext_vector_type(2))) v; unsigned u; } c;
    c.v = __builtin_amdgcn_cvt_pkrtz(a, b);
    return c.u;
}

__device__ __forceinline__ void store4(_Float16* p, v4f a) {
    union { _Float16 h[4]; uint2 u; } c;
    c.h[0] = (_Float16)a[0]; c.h[1] = (_Float16)a[1];
    c.h[2] = (_Float16)a[2]; c.h[3] = (_Float16)a[3];
    *(uint2*)p = c.u;
}

__device__ __forceinline__ void store4abs(_Float16* p, v4f a) {
    union { _Float16 h[4]; uint2 u; } c;
    c.h[0] = (_Float16)fabsf(a[0]); c.h[1] = (_Float16)fabsf(a[1]);
    c.h[2] = (_Float16)fabsf(a[2]); c.h[3] = (_Float16)fabsf(a[3]);
    *(uint2*)p = c.u;
}

// float -> bf16 bits, round-to-nearest-even (input non-NaN)
__device__ __forceinline__ unsigned short f2bf(float f) {
    unsigned b = __float_as_uint(f);
    b = (b + 0x7fffu + ((b >> 16) & 1u)) >> 16;
    return (unsigned short)b;
}

__device__ __forceinline__ int refl(int g) {
    return g < 0 ? -g : (g >= IMG ? 2 * IMG - 2 - g : g);
}

// ================= FUSED persistent cooperative kernel =================
// Stage1 tiles (grid-stride over 3072), grid.sync, stage2 chunks (768 x 16 rows).
__global__ __launch_bounds__(512, 6) void stego_fused(
    const float* __restrict__ x, const float* __restrict__ hpdf,
    unsigned short* __restrict__ rho_out, float2* __restrict__ bmm,
    float* __restrict__ out)
{
    __shared__ __align__(16) _Float16 pool[POOLSZ];
    __shared__ float red[16];

    const int tid = threadIdx.x;
    const int lane = tid & 63;
    const int wid = __builtin_amdgcn_readfirstlane(tid >> 6);
    const int n16 = lane & 15, quad = lane >> 4;

    // ---- fragment-window table (built once; B overwrites it later, regs persist) ----
    for (int e = tid; e < 1312; e += 512) {
        const int mode = e / 328;
        const int rem  = e - mode * 328;
        const int tap  = (rem >> 3) + (rem & 7) - 16;
        float v = 0.f;
        if (tap >= 0 && tap <= 15) {
            int idx = (mode == 0 || mode == 2) ? tap : 15 - tap;
            float c = hpdf[idx];
            if (mode == 1 && (tap & 1)) c = -c;
            if (mode >= 2) c = fabsf(c);
            v = c;
        }
        pool[SA_FT + e] = (_Float16)v;
    }
    __syncthreads();

    v8h band[4], bandA[2];
    {
        const int sA = 16 + quad * 8 - n16;
        #pragma unroll
        for (int m = 0; m < 4; ++m)
            band[m] = load8(pool + SA_FT + (m * 41 + sA) * 8);
        #pragma unroll
        for (int m = 0; m < 2; ++m)
            bandA[m] = load8(pool + SA_FT + (m * 41 + sA - 1) * 8);
    }

    // ---------------- stage1: grid-stride over 3072 tiles ----------------
    for (int T = blockIdx.x; T < NIMG * 128; T += gridDim.x) {
        const int c = T & 7, s = T >> 3;
        const int img = c + ((s >> 7) << 3);   // XCD slot c serves images {c, c+8, c+16}
        const int tl  = s & 127;
        const int Oi = (tl >> 4) << 6;
        const int Oj = (tl & 15) << 5;
        const float* ximg = x + (size_t)img * (IMG * IMG);

        // ---- stage X: rows Oi-15..Oi+78 (94), cols Oj-16..Oj+47 (64); rows 94..95 zero ----
        {
            const int cg2 = tid & 15, row0 = tid >> 4;
            const int c0 = Oj - 16 + 4 * cg2;
            _Float16* dst = pool + SA_X + row0 * XST + 4 * cg2;
            if (Oi >= 15 && Oi <= 433 && Oj >= 16 && Oj <= 464) {
                const float* src = ximg + (size_t)(Oi - 15 + row0) * IMG + c0;
                #pragma unroll
                for (int k = 0; k < 3; ++k) {
                    const int row = row0 + (k << 5);
                    uint2 pv = make_uint2(0u, 0u);
                    if (row < 94) {
                        float4 xv = *(const float4*)(src + (size_t)(k << 5) * IMG);
                        pv.x = pkrtz(xv.x, xv.y);
                        pv.y = pkrtz(xv.z, xv.w);
                    }
                    *(uint2*)(dst + (size_t)(k << 5) * XST) = pv;
                }
            } else {
                const int gj0 = refl(c0),     gj1 = refl(c0 + 1);
                const int gj2 = refl(c0 + 2), gj3 = refl(c0 + 3);
                #pragma unroll
                for (int k = 0; k < 3; ++k) {
                    const int row = row0 + (k << 5);
                    uint2 pv = make_uint2(0u, 0u);
                    if (row < 94) {
                        const float* rsrc = ximg + (size_t)refl(Oi - 15 + row) * IMG;
                        pv.x = pkrtz(rsrc[gj0], rsrc[gj1]);
                        pv.y = pkrtz(rsrc[gj2], rsrc[gj3]);
                    }
                    *(uint2*)(dst + (size_t)(k << 5) * XST) = pv;
                }
            }
        }
        __syncthreads();

        // ---- phase A: hconv X -> T_L', T_H' ----
        {
            const int laneX = n16 * XST + quad * 8;
            const int laneT = n16 * TST + quad * 4;
            const int u0 = wid, u1 = wid + 8, u2 = wid + 16;
            const int lo0 = (u0 % 6) * 16 * XST + (u0 / 6) * 16;
            const int lo1 = (u1 % 6) * 16 * XST + (u1 / 6) * 16;
            const int lo2 = (u2 % 6) * 16 * XST + (u2 / 6) * 16;
            const int so0 = (u0 / 6) * 16 * TST + (u0 % 6) * 16;
            const int so1 = (u1 / 6) * 16 * TST + (u1 % 6) * 16;
            const int so2 = (u2 / 6) * 16 * TST + (u2 % 6) * 16;
            v8h a0 = load8(pool + SA_X + lo0 + laneX);
            v8h a1 = load8(pool + SA_X + lo1 + laneX);
            v8h a2;
            if (wid < 2) a2 = load8(pool + SA_X + lo2 + laneX);
            const v4f z = {0.f, 0.f, 0.f, 0.f};
            v4f cL0 = __builtin_amdgcn_mfma_f32_16x16x32_f16(a0, bandA[1], z, 0, 0, 0);
            v4f cH0 = __builtin_amdgcn_mfma_f32_16x16x32_f16(a0, bandA[0], z, 0, 0, 0);
            v4f cL1 = __builtin_amdgcn_mfma_f32_16x16x32_f16(a1, bandA[1], z, 0, 0, 0);
            v4f cH1 = __builtin_amdgcn_mfma_f32_16x16x32_f16(a1, bandA[0], z, 0, 0, 0);
            store4(pool + SA_TL + so0 + laneT, cL0);
            store4(pool + SA_TH + so0 + laneT, cH0);
            store4(pool + SA_TL + so1 + laneT, cL1);
            store4(pool + SA_TH + so1 + laneT, cH1);
            if (wid < 2) {
                v4f cL2 = __builtin_amdgcn_mfma_f32_16x16x32_f16(a2, bandA[1], z, 0, 0, 0);
                v4f cH2 = __builtin_amdgcn_mfma_f32_16x16x32_f16(a2, bandA[0], z, 0, 0, 0);
                store4(pool + SA_TL + so2 + laneT, cL2);
                store4(pool + SA_TH + so2 + laneT, cH2);
            }
        }
        __syncthreads();

        // ---- phase B: vconv T -> R_f = |.| (45 tasks flat) ----
        {
            const int laneTB = n16 * TST + quad * 8;
            const int laneR  = n16 * RST + quad * 4;
            int ulo[6], uso[6], uf[6];
            #pragma unroll
            for (int k = 0; k < 6; ++k) {
                const int v = (k < 5) ? (wid + 8 * k) : (40 + wid);
                const int f = v / 15, rem = v - 15 * f;
                const int i0 = (rem % 5) * 16, c0 = (rem / 5) * 16;
                ulo[k] = (f == 0 ? SA_TL : SA_TH) + c0 * TST + i0;
                uso[k] = SA_R + f * RSZ + i0 * RST + c0;
                uf[k]  = f;
            }
            v8h aB[6];
            #pragma unroll
            for (int k = 0; k < 6; ++k)
                if (k < 5 || wid < 5) aB[k] = load8(pool + ulo[k] + laneTB);
            #pragma unroll
            for (int k = 0; k < 6; ++k)
                if (k < 5 || wid < 5) {
                    const v4f z = {0.f, 0.f, 0.f, 0.f};
                    v4f acc = __builtin_amdgcn_mfma_f32_16x16x32_f16(
                        aB[k], (uf[k] == 1) ? band[1] : band[0], z, 0, 0, 0);
                    store4abs(pool + uso[k] + laneR, acc);
                }
        }
        __syncthreads();

        // ---- phase C: hconv R_f -> U'_f (30 tasks flat) ----
        {
            const int laneRC = n16 * RST + quad * 8;
            const int laneU  = n16 * UST + quad * 4;
            int ulo[4], uso[4], uf[4];
            #pragma unroll
            for (int k = 0; k < 4; ++k) {
                const int v = (k < 3) ? (wid + 8 * k) : (24 + wid);
                const int f = v / 10, rem = v - 10 * f;
                const int i0 = (rem % 5) * 16, j0 = (rem / 5) * 16;
                ulo[k] = SA_R + f * RSZ + i0 * RST + j0;
                uso[k] = SA_U + f * USZ + j0 * UST + i0;
                uf[k]  = f;
            }
            v8h aC[4];
            #pragma unroll
            for (int k = 0; k < 4; ++k)
                if (k < 3 || wid < 6) aC[k] = load8(pool + ulo[k] + laneRC);
            #pragma unroll
            for (int k = 0; k < 4; ++k)
                if (k < 3 || wid < 6) {
                    const v4f z = {0.f, 0.f, 0.f, 0.f};
                    v4f acc = __builtin_amdgcn_mfma_f32_16x16x32_f16(
                        aC[k], (uf[k] == 0) ? band[2] : band[3], z, 0, 0, 0);
                    store4(pool + uso[k] + laneU, acc);
                }
        }
        __syncthreads();

        // ---- phase D: vconv U_f -> xi; rho = sum 1/xi ----
        float rho[4];
        {
            const int i0 = (wid & 3) * 16, c0 = (wid >> 2) * 16;
            const int laneUD = n16 * UST + quad * 8;
            const int ub = c0 * UST + i0 + laneUD;
            v8h d0 = load8(pool + SA_U + 0 * USZ + ub);
            v8h d1 = load8(pool + SA_U + 1 * USZ + ub);
            v8h d2 = load8(pool + SA_U + 2 * USZ + ub);
            const v4f z = {0.f, 0.f, 0.f, 0.f};
            v4f x0 = __builtin_amdgcn_mfma_f32_16x16x32_f16(d0, band[3], z, 0, 0, 0);
            v4f x1 = __builtin_amdgcn_mfma_f32_16x16x32_f16(d1, band[2], z, 0, 0, 0);
            v4f x2 = __builtin_amdgcn_mfma_f32_16x16x32_f16(d2, band[3], z, 0, 0, 0);
            #pragma unroll
            for (int r = 0; r < 4; ++r)
                rho[r] = __builtin_amdgcn_rcpf(x0[r]) + __builtin_amdgcn_rcpf(x1[r])
                       + __builtin_amdgcn_rcpf(x2[r]);
        }

        // ---- finalize tile: clamp/NaN, bf16 round, natural-layout store, minmax ----
        const size_t rbase = (size_t)img * (IMG * IMG);
        const int i_nat = Oi + (wid & 3) * 16 + n16;
        const int jb = Oj + ((wid >> 2) << 4) + quad * 4;
        float lmin = 1e38f, lmax = 0.f;
        unsigned pk0, pk1;
        {
            unsigned short b[4];
            #pragma unroll
            for (int r = 0; r < 4; ++r) {
                float v = rho[r];
                v = isnan(v) ? 1e10f : fminf(v, 1e10f);
                b[r] = f2bf(v);
                float rq = __uint_as_float((unsigned)b[r] << 16);
                lmin = fminf(lmin, rq);
                lmax = fmaxf(lmax, rq);
            }
            pk0 = (unsigned)b[0] | ((unsigned)b[1] << 16);
            pk1 = (unsigned)b[2] | ((unsigned)b[3] << 16);
        }
        *(uint2*)(rho_out + rbase + ((size_t)i_nat << 9) + jb) = make_uint2(pk0, pk1);

        #pragma unroll
        for (int off = 32; off >= 1; off >>= 1) {
            lmin = fminf(lmin, __shfl_xor(lmin, off));
            lmax = fmaxf(lmax, __shfl_xor(lmax, off));
        }
        if ((tid & 63) == 0) { red[wid] = lmin; red[8 + wid] = lmax; }
        __syncthreads();
        if (tid == 0) {
            float m0 = red[0], m1 = red[8];
            #pragma unroll
            for (int k = 1; k < 8; ++k) { m0 = fminf(m0, red[k]); m1 = fmaxf(m1, red[8 + k]); }
            bmm[(img << 7) + tl] = make_float2(m0, m1);
        }
        // no trailing barrier: next staging writes SA_X, disjoint from D's U reads,
        // and >=4 barriers separate red[] / pool hazards.
    }

    // ---------------- grid-wide sync: rho + bmm visible everywhere ----------------
    __threadfence();
    cg::this_grid().sync();

    // ---------------- stage2: grid-stride over 768 chunks of 16 rows ----------------
    for (int T2 = blockIdx.x; T2 < 768; T2 += gridDim.x) {
        const int c2 = T2 & 7, s2 = T2 >> 3;          // s2 in [0,96)
        const int img2 = c2 + ((s2 >> 5) << 3);        // same XCD slot as stage1 producer
        const int q2 = s2 & 31;                        // 16-row chunk index

        float lmn = 1e38f, lmx = 0.f;
        if (tid < 128) { float2 p = bmm[(img2 << 7) + tid]; lmn = p.x; lmx = p.y; }
        #pragma unroll
        for (int off = 32; off >= 1; off >>= 1) {
            lmn = fminf(lmn, __shfl_xor(lmn, off));
            lmx = fmaxf(lmx, __shfl_xor(lmx, off));
        }
        if (tid < 128 && (tid & 63) == 0) { red[tid >> 6] = lmn; red[4 + (tid >> 6)] = lmx; }
        __syncthreads();
        const float mn = fminf(red[0], red[1]);
        const float mx = fmaxf(red[4], red[5]);
        const float inv = __builtin_amdgcn_rcpf(mx - mn + 1e-8f);

        const size_t ib = (size_t)img2 << 18;
        #pragma unroll
        for (int rr = 0; rr < 2; ++rr) {
            const int row = (q2 << 4) + (wid << 1) + rr;   // one wave == one 512-px row
            const int rrow = (row - 1) & 511;
            uint4 rb = *(const uint4*)(rho_out + ib + ((size_t)rrow << 9) + (lane << 3));
            unsigned ru[4] = {rb.x, rb.y, rb.z, rb.w};
            float f7 = __uint_as_float(ru[3] & 0xffff0000u);
            float r[8];
            r[0] = __shfl(f7, (lane + 63) & 63);
            r[1] = __uint_as_float(ru[0] << 16);
            r[2] = __uint_as_float(ru[0] & 0xffff0000u);
            r[3] = __uint_as_float(ru[1] << 16);
            r[4] = __uint_as_float(ru[1] & 0xffff0000u);
            r[5] = __uint_as_float(ru[2] << 16);
            r[6] = __uint_as_float(ru[2] & 0xffff0000u);
            r[7] = __uint_as_float(ru[3] << 16);

            const size_t pbase = ib + ((size_t)row << 9) + (lane << 3);
            const float* xrow = x + pbase;
            float4 xa = *(const float4*)xrow;
            float4 xb = *(const float4*)(xrow + 4);
            float xs[8] = {xa.x, xa.y, xa.z, xa.w, xb.x, xb.y, xb.z, xb.w};
            float os[8];
            #pragma unroll
            for (int k = 0; k < 8; ++k) {
                float rn = (r[k] - mn) * inv;
                os[k] = xs[k] * __builtin_amdgcn_rcpf(1.f + __expf(rn - 1.f));
            }
            float* orow = out + pbase;
            *(float4*)orow       = make_float4(os[0], os[1], os[2], os[3]);
            *(float4*)(orow + 4) = make_float4(os[4], os[5], os[6], os[7]);
        }
        __syncthreads();   // red[] reuse when a block runs multiple chunks
    }
}

// ================= FALLBACK: proven two-kernel pair (R5) =================
__global__ __launch_bounds__(512, 6) void stego_stage1(
    const float* __restrict__ x, const float* __restrict__ hpdf,
    unsigned short* __restrict__ rho_out, float2* __restrict__ bmm)
{
    __shared__ __align__(16) _Float16 pool[POOLSZ];
    __shared__ float red[16];

    const int tid = threadIdx.x;
    const int lane = tid & 63;
    const int wid = __builtin_amdgcn_readfirstlane(tid >> 6);
    const int n16 = lane & 15, quad = lane >> 4;

    const int blk = blockIdx.x;
    const int xcd = blk & 7;
    const int grp = blk >> 3;
    const int img = xcd + ((grp >> 7) << 3);
    const int tl  = grp & 127;
    const int Oi = (tl >> 4) << 6;
    const int Oj = (tl & 15) << 5;
    const float* ximg = x + (size_t)img * (IMG * IMG);

    for (int e = tid; e < 1312; e += 512) {
        const int mode = e / 328;
        const int rem  = e - mode * 328;
        const int tap  = (rem >> 3) + (rem & 7) - 16;
        float v = 0.f;
        if (tap >= 0 && tap <= 15) {
            int idx = (mode == 0 || mode == 2) ? tap : 15 - tap;
            float c = hpdf[idx];
            if (mode == 1 && (tap & 1)) c = -c;
            if (mode >= 2) c = fabsf(c);
            v = c;
        }
        pool[SA_FT + e] = (_Float16)v;
    }

    {
        const int cg2 = tid & 15, row0 = tid >> 4;
        const int c0 = Oj - 16 + 4 * cg2;
        _Float16* dst = pool + SA_X + row0 * XST + 4 * cg2;
        if (Oi >= 15 && Oi <= 433 && Oj >= 16 && Oj <= 464) {
            const float* src = ximg + (size_t)(Oi - 15 + row0) * IMG + c0;
            #pragma unroll
            for (int k = 0; k < 3; ++k) {
                const int row = row0 + (k << 5);
                uint2 pv = make_uint2(0u, 0u);
                if (row < 94) {
                    float4 xv = *(const float4*)(src + (size_t)(k << 5) * IMG);
                    pv.x = pkrtz(xv.x, xv.y);
                    pv.y = pkrtz(xv.z, xv.w);
                }
                *(uint2*)(dst + (size_t)(k << 5) * XST) = pv;
            }
        } else {
            const int gj0 = refl(c0),     gj1 = refl(c0 + 1);
            const int gj2 = refl(c0 + 2), gj3 = refl(c0 + 3);
            #pragma unroll
            for (int k = 0; k < 3; ++k) {
                const int row = row0 + (k << 5);
                uint2 pv = make_uint2(0u, 0u);
                if (row < 94) {
                    const float* rsrc = ximg + (size_t)refl(Oi - 15 + row) * IMG;
                    pv.x = pkrtz(rsrc[gj0], rsrc[gj1]);
                    pv.y = pkrtz(rsrc[gj2], rsrc[gj3]);
                }
                *(uint2*)(dst + (size_t)(k << 5) * XST) = pv;
            }
        }
    }
    __syncthreads();

    v8h band[4], bandA[2];
    {
        const int sA = 16 + quad * 8 - n16;
        #pragma unroll
        for (int m = 0; m < 4; ++m)
            band[m] = load8(pool + SA_FT + (m * 41 + sA) * 8);
        #pragma unroll
        for (int m = 0; m < 2; ++m)
            bandA[m] = load8(pool + SA_FT + (m * 41 + sA - 1) * 8);
    }

    {
        const int laneX = n16 * XST + quad * 8;
        const int laneT = n16 * TST + quad * 4;
        const int u0 = wid, u1 = wid + 8, u2 = wid + 16;
        const int lo0 = (u0 % 6) * 16 * XST + (u0 / 6) * 16;
        const int lo1 = (u1 % 6) * 16 * XST + (u1 / 6) * 16;
        const int lo2 = (u2 % 6) * 16 * XST + (u2 / 6) * 16;
        const int so0 = (u0 / 6) * 16 * TST + (u0 % 6) * 16;
        const int so1 = (u1 / 6) * 16 * TST + (u1 % 6) * 16;
        const int so2 = (u2 / 6) * 16 * TST + (u2 % 6) * 16;
        v8h a0 = load8(pool + SA_X + lo0 + laneX);
        v8h a1 = load8(pool + SA_X + lo1 + laneX);
        v8h a2;
        if (wid < 2) a2 = load8(pool + SA_X + lo2 + laneX);
        const v4f z = {0.f, 0.f, 0.f, 0.f};
        v4f cL0 = __builtin_amdgcn_mfma_f32_16x16x32_f16(a0, bandA[1], z, 0, 0, 0);
        v4f cH0 = __builtin_amdgcn_mfma_f32_16x16x32_f16(a0, bandA[0], z, 0, 0, 0);
        v4f cL1 = __builtin_amdgcn_mfma_f32_16x16x32_f16(a1, bandA[1], z, 0, 0, 0);
        v4f cH1 = __builtin_amdgcn_mfma_f32_16x16x32_f16(a1, bandA[0], z, 0, 0, 0);
        store4(pool + SA_TL + so0 + laneT, cL0);
        store4(pool + SA_TH + so0 + laneT, cH0);
        store4(pool + SA_TL + so1 + laneT, cL1);
        store4(pool + SA_TH + so1 + laneT, cH1);
        if (wid < 2) {
            v4f cL2 = __builtin_amdgcn_mfma_f32_16x16x32_f16(a2, bandA[1], z, 0, 0, 0);
            v4f cH2 = __builtin_amdgcn_mfma_f32_16x16x32_f16(a2, bandA[0], z, 0, 0, 0);
            store4(pool + SA_TL + so2 + laneT, cL2);
            store4(pool + SA_TH + so2 + laneT, cH2);
        }
    }
    __syncthreads();

    {
        const int laneTB = n16 * TST + quad * 8;
        const int laneR  = n16 * RST + quad * 4;
        int ulo[6], uso[6], uf[6];
        #pragma unroll
        for (int k = 0; k < 6; ++k) {
            const int v = (k < 5) ? (wid + 8 * k) : (40 + wid);
            const int f = v / 15, rem = v - 15 * f;
            const int i0 = (rem % 5) * 16, c0 = (rem / 5) * 16;
            ulo[k] = (f == 0 ? SA_TL : SA_TH) + c0 * TST + i0;
            uso[k] = SA_R + f * RSZ + i0 * RST + c0;
            uf[k]  = f;
        }
        v8h aB[6];
        #pragma unroll
        for (int k = 0; k < 6; ++k)
            if (k < 5 || wid < 5) aB[k] = load8(pool + ulo[k] + laneTB);
        #pragma unroll
        for (int k = 0; k < 6; ++k)
            if (k < 5 || wid < 5) {
                const v4f z = {0.f, 0.f, 0.f, 0.f};
                v4f acc = __builtin_amdgcn_mfma_f32_16x16x32_f16(
                    aB[k], (uf[k] == 1) ? band[1] : band[0], z, 0, 0, 0);
                store4abs(pool + uso[k] + laneR, acc);
            }
    }
    __syncthreads();

    {
        const int laneRC = n16 * RST + quad * 8;
        const int laneU  = n16 * UST + quad * 4;
        int ulo[4], uso[4], uf[4];
        #pragma unroll
        for (int k = 0; k < 4; ++k) {
            const int v = (k < 3) ? (wid + 8 * k) : (24 + wid);
            const int f = v / 10, rem = v - 10 * f;
            const int i0 = (rem % 5) * 16, j0 = (rem / 5) * 16;
            ulo[k] = SA_R + f * RSZ + i0 * RST + j0;
            uso[k] = SA_U + f * USZ + j0 * UST + i0;
            uf[k]  = f;
        }
        v8h aC[4];
        #pragma unroll
        for (int k = 0; k < 4; ++k)
            if (k < 3 || wid < 6) aC[k] = load8(pool + ulo[k] + laneRC);
        #pragma unroll
        for (int k = 0; k < 4; ++k)
            if (k < 3 || wid < 6) {
                const v4f z = {0.f, 0.f, 0.f, 0.f};
                v4f acc = __builtin_amdgcn_mfma_f32_16x16x32_f16(
                    aC[k], (uf[k] == 0) ? band[2] : band[3], z, 0, 0, 0);
                store4(pool + uso[k] + laneU, acc);
            }
    }
    __syncthreads();

    float rho[4];
    {
        const int i0 = (wid & 3) * 16, c0 = (wid >> 2) * 16;
        const int laneUD = n16 * UST + quad * 8;
        const int ub = c0 * UST + i0 + laneUD;
        v8h d0 = load8(pool + SA_U + 0 * USZ + ub);
        v8h d1 = load8(pool + SA_U + 1 * USZ + ub);
        v8h d2 = load8(pool + SA_U + 2 * USZ + ub);
        const v4f z = {0.f, 0.f, 0.f, 0.f};
        v4f x0 = __builtin_amdgcn_mfma_f32_16x16x32_f16(d0, band[3], z, 0, 0, 0);
        v4f x1 = __builtin_amdgcn_mfma_f32_16x16x32_f16(d1, band[2], z, 0, 0, 0);
        v4f x2 = __builtin_amdgcn_mfma_f32_16x16x32_f16(d2, band[3], z, 0, 0, 0);
        #pragma unroll
        for (int r = 0; r < 4; ++r)
            rho[r] = __builtin_amdgcn_rcpf(x0[r]) + __builtin_amdgcn_rcpf(x1[r])
                   + __builtin_amdgcn_rcpf(x2[r]);
    }

    const size_t rbase = (size_t)img * (IMG * IMG);
    const int i_nat = Oi + (wid & 3) * 16 + n16;
    const int jb = Oj + ((wid >> 2) << 4) + quad * 4;
    float lmin = 1e38f, lmax = 0.f;
    unsigned pk0, pk1;
    {
        unsigned short b[4];
        #pragma unroll
        for (int r = 0; r < 4; ++r) {
            float v = rho[r];
            v = isnan(v) ? 1e10f : fminf(v, 1e10f);
            b[r] = f2bf(v);
            float rq = __uint_as_float((unsigned)b[r] << 16);
            lmin = fminf(lmin, rq);
            lmax = fmaxf(lmax, rq);
        }
        pk0 = (unsigned)b[0] | ((unsigned)b[1] << 16);
        pk1 = (unsigned)b[2] | ((unsigned)b[3] << 16);
    }
    *(uint2*)(rho_out + rbase + ((size_t)i_nat << 9) + jb) = make_uint2(pk0, pk1);

    #pragma unroll
    for (int off = 32; off >= 1; off >>= 1) {
        lmin = fminf(lmin, __shfl_xor(lmin, off));
        lmax = fmaxf(lmax, __shfl_xor(lmax, off));
    }
    if ((tid & 63) == 0) { red[wid] = lmin; red[8 + wid] = lmax; }
    __syncthreads();
    if (tid == 0) {
        float m0 = red[0], m1 = red[8];
        #pragma unroll
        for (int k = 1; k < 8; ++k) { m0 = fminf(m0, red[k]); m1 = fmaxf(m1, red[8 + k]); }
        bmm[(img << 7) + tl] = make_float2(m0, m1);
    }
}

__global__ __launch_bounds__(256) void stego_stage2(
    const float* __restrict__ x, const unsigned short* __restrict__ rho,
    const float2* __restrict__ bmm, float* __restrict__ out)
{
    __shared__ float sred[8];
    const int tid = threadIdx.x;
    const int lane = tid & 63;

    const int blk = blockIdx.x;
    const int xcd = blk & 7, grp = blk >> 3;
    const int img = xcd + ((grp >> 7) << 3);
    const int chunk = grp & 127;
    const int t = (img << 15) + (chunk << 8) + tid;

    float lmn = 1e38f, lmx = 0.f;
    if (tid < 128) { float2 p = bmm[(img << 7) + tid]; lmn = p.x; lmx = p.y; }
    #pragma unroll
    for (int off = 32; off >= 1; off >>= 1) {
        lmn = fminf(lmn, __shfl_xor(lmn, off));
        lmx = fmaxf(lmx, __shfl_xor(lmx, off));
    }
    if (tid < 128 && (tid & 63) == 0) { sred[tid >> 6] = lmn; sred[4 + (tid >> 6)] = lmx; }
    __syncthreads();
    const float mn = fminf(sred[0], sred[1]);
    const float mx = fmaxf(sred[4], sred[5]);
    const float inv = __builtin_amdgcn_rcpf(mx - mn + 1e-8f);

    const int i = (t >> 6) & 511;
    const int rrow = (i - 1) & 511;
    const size_t rb_off = ((size_t)img << 18) + ((size_t)rrow << 9) + ((size_t)lane << 3);
    uint4 rb = *(const uint4*)(rho + rb_off);
    unsigned ru[4] = {rb.x, rb.y, rb.z, rb.w};
    float f7 = __uint_as_float(ru[3] & 0xffff0000u);
    float r[8];
    r[0] = __shfl(f7, (lane + 63) & 63);
    r[1] = __uint_as_float(ru[0] << 16);
    r[2] = __uint_as_float(ru[0] & 0xffff0000u);
    r[3] = __uint_as_float(ru[1] << 16);
    r[4] = __uint_as_float(ru[1] & 0xffff0000u);
    r[5] = __uint_as_float(ru[2] << 16);
    r[6] = __uint_as_float(ru[2] & 0xffff0000u);
    r[7] = __uint_as_float(ru[3] << 16);

    const size_t base = (size_t)t << 3;
    const float* xrow = x + base;
    float4 xa = *(const float4*)xrow;
    float4 xb = *(const float4*)(xrow + 4);
    float xs[8] = {xa.x, xa.y, xa.z, xa.w, xb.x, xb.y, xb.z, xb.w};
    float os[8];
    #pragma unroll
    for (int k = 0; k < 8; ++k) {
        float rn = (r[k] - mn) * inv;
        os[k] = xs[k] * __builtin_amdgcn_rcpf(1.f + __expf(rn - 1.f));
    }
    float* orow = out + base;
    *(float4*)orow       = make_float4(os[0], os[1], os[2], os[3]);
    *(float4*)(orow + 4) = make_float4(os[4], os[5], os[6], os[7]);
}

extern "C" void kernel_launch(void* const* d_in, const int* in_sizes, int n_in,
                              void* d_out, int out_size, void* d_ws, size_t ws_size,
                              hipStream_t stream) {
    const float* x    = (const float*)d_in[0];
    const float* hpdf = (const float*)d_in[1];
    float* out = (float*)d_out;

    unsigned short* rho = (unsigned short*)d_ws;                         // 24*512*512 bf16
    float2* bmm = (float2*)((char*)d_ws + (size_t)NIMG * IMG * IMG * 2); // 24*128 float2

    // Preferred: persistent cooperative fused kernel (1 dispatch, in-kernel grid sync).
    int nb = 0;
    hipError_t e = hipOccupancyMaxActiveBlocksPerMultiprocessor(
        &nb, reinterpret_cast<const void*>(stego_fused), 512, 0);
    bool done = false;
    if (e == hipSuccess && nb >= 1) {
        if (nb > 3) nb = 3;
        dim3 grid(256 * nb);                 // 256|512|768 — all divide 3072 tiles
        void* args[] = {(void*)&x, (void*)&hpdf, (void*)&rho, (void*)&bmm, (void*)&out};
        e = hipLaunchCooperativeKernel(reinterpret_cast<const void*>(stego_fused),
                                       grid, dim3(512), args, 0, stream);
        done = (e == hipSuccess);
    }
    if (!done) {
        // Fallback: proven two-kernel path (R5).
        hipLaunchKernelGGL(stego_stage1, dim3(NIMG * 128), dim3(512), 0, stream,
                           x, hpdf, rho, bmm);
        hipLaunchKernelGGL(stego_stage2, dim3(NIMG * 128), dim3(256), 0, stream,
                           x, rho, bmm, out);
    }
}

// Round 7
// 123.068 us; speedup vs baseline: 2.2732x; 2.2732x over previous
//
#include <hip/hip_runtime.h>
#include <math.h>

#define IMG   512
#define NIMG  24
#define TST   104    // T' stride (row length 96)
#define RST   56     // R stride (row length 48)
#define UST   88     // U' stride (row length 80)

// ---- LDS pool layout (units: halfs), 32x64 output tile, overlapped buffers ----
// live ranges: TL:A->Bf0  TH:A->Bf12  R0:Bf0->Cf0  R1:Bf12->Cf1  R2:Bf12->Cf2
//              U0,U1,U2:C->D   FT: init->frag-load (dead before R2 write)
#define SA_TL  0        // 48*104 = 4992
#define SA_TH  4992     // -> 9984
#define SA_R0  9984     // 80*56 = 4480 -> 14464
#define SA_R1  0        // over TL (dead after B-f0 barrier)
#define SA_R2  14464    // -> 18944 (over dead FT)
#define SA_U0  4992     // 32*88 = 2816, over TH (dead after B-f12 barrier)
#define SA_U1  9984     // over R0 (dead after C-f0 barrier)
#define SA_U2  0        // over R1 (dead after C-f1 barrier)
#define SA_FT  14464    // 1312 halfs; dead after frag load, overwritten by R2
#define POOLSZ 18944    // 37888 B + red -> 4 blocks/CU (needs VGPR<=64)

typedef _Float16 v8h __attribute__((ext_vector_type(8)));
typedef float    v4f __attribute__((ext_vector_type(4)));

__device__ __forceinline__ v8h load8(const _Float16* p) {
    union { uint4 u; v8h h; } c;
    c.u = *(const uint4*)p;
    return c.h;
}

__device__ __forceinline__ unsigned pkrtz(float a, float b) {
    union { __fp16 __attribute__((ext_vector_type(2))) v; unsigned u; } c;
    c.v = __builtin_amdgcn_cvt_pkrtz(a, b);
    return c.u;
}

__device__ __forceinline__ void store4(_Float16* p, v4f a) {
    union { _Float16 h[4]; uint2 u; } c;
    c.h[0] = (_Float16)a[0]; c.h[1] = (_Float16)a[1];
    c.h[2] = (_Float16)a[2]; c.h[3] = (_Float16)a[3];
    *(uint2*)p = c.u;
}

__device__ __forceinline__ void store4abs(_Float16* p, v4f a) {
    union { _Float16 h[4]; uint2 u; } c;
    c.h[0] = (_Float16)fabsf(a[0]); c.h[1] = (_Float16)fabsf(a[1]);
    c.h[2] = (_Float16)fabsf(a[2]); c.h[3] = (_Float16)fabsf(a[3]);
    *(uint2*)p = c.u;
}

// float -> bf16 bits, round-to-nearest-even (input non-NaN)
__device__ __forceinline__ unsigned short f2bf(float f) {
    unsigned b = __float_as_uint(f);
    b = (b + 0x7fffu + ((b >> 16) & 1u)) >> 16;
    return (unsigned short)b;
}

__device__ __forceinline__ int refl(int g) {
    return g < 0 ? -g : (g >= IMG ? 2 * IMG - 2 - g : g);
}

// ---------------- stage 1: MFMA banded-conv, no X staging, 4 blocks/CU ----------------
// modes: 0: h[v]  1: lpdf[v]=(-1)^v h[15-v]  2: |h[v]|  3: |h[15-v]|
__global__ __launch_bounds__(512, 8) void stego_stage1(
    const float* __restrict__ x, const float* __restrict__ hpdf,
    unsigned short* __restrict__ rho_out, float2* __restrict__ bmm)
{
    __shared__ __align__(16) _Float16 pool[POOLSZ];
    __shared__ float red[16];

    const int tid = threadIdx.x;
    const int lane = tid & 63;
    const int wid = __builtin_amdgcn_readfirstlane(tid >> 6);   // wave-uniform -> SALU
    const int n16 = lane & 15, quad = lane >> 4;

    // XCD-swizzled block decode: all 128 tiles of an image land on one XCD's L2
    const int blk = blockIdx.x;
    const int xcd = blk & 7;
    const int grp = blk >> 3;                 // 0..383
    const int img = xcd + ((grp >> 7) << 3);  // XCD c serves images {c, c+8, c+16}
    const int tl  = grp & 127;
    const int Oi = (tl >> 4) << 6;
    const int Oj = (tl & 15) << 5;
    const float* ximg = x + (size_t)img * (IMG * IMG);
    const bool interior = (Oi >= 15 && Oi <= 433 && Oj >= 16 && Oj <= 464);

    // ---- fragment-window table: ftab[(mode*41 + s)*8 + j] = c_mode[s + j - 16] ----
    for (int e = tid; e < 1312; e += 512) {
        const int mode = e / 328;
        const int rem  = e - mode * 328;
        const int tap  = (rem >> 3) + (rem & 7) - 16;      // s + j - 16
        float v = 0.f;
        if (tap >= 0 && tap <= 15) {
            int idx = (mode == 0 || mode == 2) ? tap : 15 - tap;
            float c = hpdf[idx];
            if (mode == 1 && (tap & 1)) c = -c;
            if (mode >= 2) c = fabsf(c);
            v = c;
        }
        pool[SA_FT + e] = (_Float16)v;
    }
    __syncthreads();   // (1) FT visible

    // ---- band fragments (one ds_read_b128 each; FT dead afterwards) ----
    // band[4]: UNSHIFTED  B[k][n] = c[k-n]    (phases B, C, D)
    // bandA[2]: SHIFTED   B[k][n] = c[k-n-1]  (phase A only; X cols start at Oj-16)
    v8h band[4], bandA[2];
    {
        const int sA = 16 + quad * 8 - n16;   // in [1,40]
        #pragma unroll
        for (int m = 0; m < 4; ++m)
            band[m] = load8(pool + SA_FT + (m * 41 + sA) * 8);
        #pragma unroll
        for (int m = 0; m < 2; ++m)
            bandA[m] = load8(pool + SA_FT + (m * 41 + sA - 1) * 8);
    }

    const v4f z = {0.f, 0.f, 0.f, 0.f};

    // ---- phase A: hconv X -> T_L', T_H' (18 tiles). A-fragments read DIRECTLY
    //      from global (2 aligned float4 + 4 pkrtz); rows >= 94 are zero pad. ----
    for (int u = wid; u < 18; u += 8) {
        const int mt = u % 6, nt = u / 6;
        const int m0 = mt * 16, n0 = nt * 16;
        const int row = m0 + n16;             // 0..95
        union { unsigned uu[4]; v8h h; } cc;
        cc.uu[0] = cc.uu[1] = cc.uu[2] = cc.uu[3] = 0u;
        if (row < 94) {
            const int gcol = Oj - 16 + n0 + quad * 8;    // 32B-aligned (mult of 8)
            if (interior) {
                const float* rp = ximg + (size_t)(Oi - 15 + row) * IMG + gcol;
                float4 xa = *(const float4*)rp;
                float4 xb = *(const float4*)(rp + 4);
                cc.uu[0] = pkrtz(xa.x, xa.y); cc.uu[1] = pkrtz(xa.z, xa.w);
                cc.uu[2] = pkrtz(xb.x, xb.y); cc.uu[3] = pkrtz(xb.z, xb.w);
            } else {
                const float* rsrc = ximg + (size_t)refl(Oi - 15 + row) * IMG;
                float xv[8];
                #pragma unroll
                for (int e = 0; e < 8; ++e) xv[e] = rsrc[refl(gcol + e)];
                cc.uu[0] = pkrtz(xv[0], xv[1]); cc.uu[1] = pkrtz(xv[2], xv[3]);
                cc.uu[2] = pkrtz(xv[4], xv[5]); cc.uu[3] = pkrtz(xv[6], xv[7]);
            }
        }
        v4f cL = __builtin_amdgcn_mfma_f32_16x16x32_f16(cc.h, bandA[1], z, 0, 0, 0);
        v4f cH = __builtin_amdgcn_mfma_f32_16x16x32_f16(cc.h, bandA[0], z, 0, 0, 0);
        const int off = (n0 + n16) * TST + m0 + quad * 4;   // T'[col][row..row+3]
        store4(pool + SA_TL + off, cL);
        store4(pool + SA_TH + off, cH);
    }
    __syncthreads();   // (2) T visible

    // ---- phase B-f0: vconv T_L -> R0 = |.| (15 tiles) ----
    for (int u = wid; u < 15; u += 8) {
        const int i0 = (u % 5) * 16, c0 = (u / 5) * 16;
        v8h a = load8(pool + SA_TL + (c0 + n16) * TST + i0 + quad * 8);
        v4f acc = __builtin_amdgcn_mfma_f32_16x16x32_f16(a, band[0], z, 0, 0, 0);
        store4abs(pool + SA_R0 + (i0 + n16) * RST + c0 + quad * 4, acc);
    }
    __syncthreads();   // (3) R0 visible; TL dead

    // ---- phase B-f1/f2: vconv T_H -> R1 (band[1]), R2 (band[0]); R1 over dead TL ----
    for (int v = wid; v < 30; v += 8) {
        const int hi = v >= 15;               // 0 -> f=1, 1 -> f=2
        const int rem = hi ? v - 15 : v;
        const int i0 = (rem % 5) * 16, c0 = (rem / 5) * 16;
        v8h a = load8(pool + SA_TH + (c0 + n16) * TST + i0 + quad * 8);
        v4f acc = __builtin_amdgcn_mfma_f32_16x16x32_f16(
            a, hi ? band[0] : band[1], z, 0, 0, 0);
        store4abs(pool + (hi ? SA_R2 : SA_R1) + (i0 + n16) * RST + c0 + quad * 4, acc);
    }
    __syncthreads();   // (4) R1,R2 visible; TH dead

    // ---- phase C-f0: hconv R0 -> U0 (band[2]); U0 over dead TH ----
    for (int u = wid; u < 10; u += 8) {
        const int i0 = (u % 5) * 16, j0 = (u / 5) * 16;
        v8h a = load8(pool + SA_R0 + (i0 + n16) * RST + j0 + quad * 8);
        v4f acc = __builtin_amdgcn_mfma_f32_16x16x32_f16(a, band[2], z, 0, 0, 0);
        store4(pool + SA_U0 + (j0 + n16) * UST + i0 + quad * 4, acc);
    }
    __syncthreads();   // (5) U0 visible; R0 dead

    // ---- phase C-f1: hconv R1 -> U1 (band[3]); U1 over dead R0 ----
    for (int u = wid; u < 10; u += 8) {
        const int i0 = (u % 5) * 16, j0 = (u / 5) * 16;
        v8h a = load8(pool + SA_R1 + (i0 + n16) * RST + j0 + quad * 8);
        v4f acc = __builtin_amdgcn_mfma_f32_16x16x32_f16(a, band[3], z, 0, 0, 0);
        store4(pool + SA_U1 + (j0 + n16) * UST + i0 + quad * 4, acc);
    }
    __syncthreads();   // (6) U1 visible; R1 dead

    // ---- phase C-f2: hconv R2 -> U2 (band[3]); U2 over dead R1 ----
    for (int u = wid; u < 10; u += 8) {
        const int i0 = (u % 5) * 16, j0 = (u / 5) * 16;
        v8h a = load8(pool + SA_R2 + (i0 + n16) * RST + j0 + quad * 8);
        v4f acc = __builtin_amdgcn_mfma_f32_16x16x32_f16(a, band[3], z, 0, 0, 0);
        store4(pool + SA_U2 + (j0 + n16) * UST + i0 + quad * 4, acc);
    }
    __syncthreads();   // (7) U2 visible; R2 dead

    // ---- phase D: vconv U_f -> xi; rho = sum 1/xi (24 tiles, 3/wave) ----
    float rho[4];
    {
        const int i0 = (wid & 3) * 16, c0 = (wid >> 2) * 16;
        const int ub = (c0 + n16) * UST + i0 + quad * 8;
        v8h d0 = load8(pool + SA_U0 + ub);
        v8h d1 = load8(pool + SA_U1 + ub);
        v8h d2 = load8(pool + SA_U2 + ub);
        v4f x0 = __builtin_amdgcn_mfma_f32_16x16x32_f16(d0, band[3], z, 0, 0, 0);  // fD[0]=3
        v4f x1 = __builtin_amdgcn_mfma_f32_16x16x32_f16(d1, band[2], z, 0, 0, 0);  // fD[1]=2
        v4f x2 = __builtin_amdgcn_mfma_f32_16x16x32_f16(d2, band[3], z, 0, 0, 0);  // fD[2]=3
        #pragma unroll
        for (int r = 0; r < 4; ++r)
            rho[r] = __builtin_amdgcn_rcpf(x0[r]) + __builtin_amdgcn_rcpf(x1[r])
                   + __builtin_amdgcn_rcpf(x2[r]);
    }

    // ---- finalize: clamp/NaN, bf16 round, NATURAL-layout aligned uint2 store;
    //      roll applied at stage2 read. Per-block min/max unchanged. ----
    const size_t rbase = (size_t)img * (IMG * IMG);
    const int i_nat = Oi + (wid & 3) * 16 + n16;
    const int jb = Oj + ((wid >> 2) << 4) + quad * 4;
    float lmin = 1e38f, lmax = 0.f;
    unsigned pk0, pk1;
    {
        unsigned short b[4];
        #pragma unroll
        for (int r = 0; r < 4; ++r) {
            float v = rho[r];
            v = isnan(v) ? 1e10f : fminf(v, 1e10f);
            b[r] = f2bf(v);
            float rq = __uint_as_float((unsigned)b[r] << 16);
            lmin = fminf(lmin, rq);
            lmax = fmaxf(lmax, rq);
        }
        pk0 = (unsigned)b[0] | ((unsigned)b[1] << 16);
        pk1 = (unsigned)b[2] | ((unsigned)b[3] << 16);
    }
    *(uint2*)(rho_out + rbase + ((size_t)i_nat << 9) + jb) = make_uint2(pk0, pk1);

    #pragma unroll
    for (int off = 32; off >= 1; off >>= 1) {
        lmin = fminf(lmin, __shfl_xor(lmin, off));
        lmax = fmaxf(lmax, __shfl_xor(lmax, off));
    }
    if ((tid & 63) == 0) { red[wid] = lmin; red[8 + wid] = lmax; }
    __syncthreads();   // (8)
    if (tid == 0) {
        float m0 = red[0], m1 = red[8];
        #pragma unroll
        for (int k = 1; k < 8; ++k) { m0 = fminf(m0, red[k]); m1 = fmaxf(m1, red[8 + k]); }
        bmm[(img << 7) + tl] = make_float2(m0, m1);
    }
}

// ---------------- stage 2: reduce minmax + rolled read + normalize + sigmoid + multiply ----------------
__global__ __launch_bounds__(256) void stego_stage2(
    const float* __restrict__ x, const unsigned short* __restrict__ rho,
    const float2* __restrict__ bmm, float* __restrict__ out)
{
    __shared__ float sred[8];
    const int tid = threadIdx.x;
    const int lane = tid & 63;

    // same XCD swizzle as stage1: read rho/x from the L2 that produced them
    const int blk = blockIdx.x;
    const int xcd = blk & 7, grp = blk >> 3;
    const int img = xcd + ((grp >> 7) << 3);
    const int chunk = grp & 127;                 // 128 blocks per image, 4 rows each
    const int t = (img << 15) + (chunk << 8) + tid;

    float lmn = 1e38f, lmx = 0.f;
    if (tid < 128) { float2 p = bmm[(img << 7) + tid]; lmn = p.x; lmx = p.y; }
    #pragma unroll
    for (int off = 32; off >= 1; off >>= 1) {
        lmn = fminf(lmn, __shfl_xor(lmn, off));
        lmx = fmaxf(lmx, __shfl_xor(lmx, off));
    }
    if (tid < 128 && (tid & 63) == 0) { sred[tid >> 6] = lmn; sred[4 + (tid >> 6)] = lmx; }
    __syncthreads();
    const float mn = fminf(sred[0], sred[1]);
    const float mx = fmaxf(sred[4], sred[5]);
    const float inv = __builtin_amdgcn_rcpf(mx - mn + 1e-8f);

    // rolled rho: rho_rolled[i][j] = rho_nat[(i-1)&511][(j-1)&511].
    // One wave == one 512-px row, so the j-1 shift is a single intra-wave shfl.
    const int i = (t >> 6) & 511;
    const int rrow = (i - 1) & 511;
    const size_t rb_off = ((size_t)img << 18) + ((size_t)rrow << 9) + ((size_t)lane << 3);
    uint4 rb = *(const uint4*)(rho + rb_off);
    unsigned ru[4] = {rb.x, rb.y, rb.z, rb.w};
    float f7 = __uint_as_float(ru[3] & 0xffff0000u);   // nat col 8*lane+7
    float r[8];
    r[0] = __shfl(f7, (lane + 63) & 63);               // prev lane's col 7 (wraps to col 511)
    r[1] = __uint_as_float(ru[0] << 16);
    r[2] = __uint_as_float(ru[0] & 0xffff0000u);
    r[3] = __uint_as_float(ru[1] << 16);
    r[4] = __uint_as_float(ru[1] & 0xffff0000u);
    r[5] = __uint_as_float(ru[2] << 16);
    r[6] = __uint_as_float(ru[2] & 0xffff0000u);
    r[7] = __uint_as_float(ru[3] << 16);

    const size_t base = (size_t)t << 3;
    const float* xrow = x + base;
    float4 xa = *(const float4*)xrow;
    float4 xb = *(const float4*)(xrow + 4);
    float xs[8] = {xa.x, xa.y, xa.z, xa.w, xb.x, xb.y, xb.z, xb.w};
    float os[8];
    #pragma unroll
    for (int k = 0; k < 8; ++k) {
        float rn = (r[k] - mn) * inv;
        os[k] = xs[k] * __builtin_amdgcn_rcpf(1.f + __expf(rn - 1.f));  // x * sigmoid(1-rn)
    }
    float* orow = out + base;
    *(float4*)orow       = make_float4(os[0], os[1], os[2], os[3]);
    *(float4*)(orow + 4) = make_float4(os[4], os[5], os[6], os[7]);
}

extern "C" void kernel_launch(void* const* d_in, const int* in_sizes, int n_in,
                              void* d_out, int out_size, void* d_ws, size_t ws_size,
                              hipStream_t stream) {
    const float* x    = (const float*)d_in[0];
    const float* hpdf = (const float*)d_in[1];
    float* out = (float*)d_out;

    unsigned short* rho = (unsigned short*)d_ws;                         // 24*512*512 bf16
    float2* bmm = (float2*)((char*)d_ws + (size_t)NIMG * IMG * IMG * 2); // 24*128 float2

    hipLaunchKernelGGL(stego_stage1, dim3(NIMG * 128), dim3(512), 0, stream,
                       x, hpdf, rho, bmm);
    hipLaunchKernelGGL(stego_stage2, dim3(NIMG * 128), dim3(256), 0, stream,
                       x, rho, bmm, out);
}

// Round 8
// 108.579 us; speedup vs baseline: 2.5766x; 1.1334x over previous
//
#include <hip/hip_runtime.h>
#include <math.h>

#define IMG   512
#define NIMG  24
#define XST   72     // X stride (halfs): rows 16B-aligned
#define TST   104    // T' stride (row length 96)
#define RST   56     // R stride (row length 48)
#define UST   88     // U' stride (row length 80)

// ---- LDS pool layout (units: halfs), 64-row x 32-col output tile ----
// A: reads X [9984,16896), writes sTL/sTH [0,9984)
// B: reads sT,              writes R0..R2 [9984,23424)  (over dead X)
// C: reads R,               writes U0..U2 [0,8448)      (over dead sT)
// D: reads U.   ftab [22112,23424) read into regs pre-A; B overwrites after barrier.
#define SA_TL  0        // 48*104 = 4992
#define SA_TH  4992     // 4992
#define SA_X   9984     // 96*72 = 6912 (dead after A)
#define SA_R   9984     // 3 x 80*56 = 13440 -> [9984, 23424)
#define RSZ    4480
#define SA_U   0        // 3 x 32*88 -> [0, 8448)
#define USZ    2816
#define SA_FT  22112    // 4 modes x 41 starts x 8 = 1312 -> [22112, 23424)
#define POOLSZ 23424    // 46848 B -> 3 blocks/CU

typedef _Float16 v8h __attribute__((ext_vector_type(8)));
typedef float    v4f __attribute__((ext_vector_type(4)));

__device__ __forceinline__ v8h load8(const _Float16* p) {
    union { uint4 u; v8h h; } c;
    c.u = *(const uint4*)p;
    return c.h;
}

__device__ __forceinline__ unsigned pkrtz(float a, float b) {
    union { __fp16 __attribute__((ext_vector_type(2))) v; unsigned u; } c;
    c.v = __builtin_amdgcn_cvt_pkrtz(a, b);
    return c.u;
}

__device__ __forceinline__ void store4(_Float16* p, v4f a) {
    union { _Float16 h[4]; uint2 u; } c;
    c.h[0] = (_Float16)a[0]; c.h[1] = (_Float16)a[1];
    c.h[2] = (_Float16)a[2]; c.h[3] = (_Float16)a[3];
    *(uint2*)p = c.u;
}

__device__ __forceinline__ void store4abs(_Float16* p, v4f a) {
    union { _Float16 h[4]; uint2 u; } c;
    c.h[0] = (_Float16)fabsf(a[0]); c.h[1] = (_Float16)fabsf(a[1]);
    c.h[2] = (_Float16)fabsf(a[2]); c.h[3] = (_Float16)fabsf(a[3]);
    *(uint2*)p = c.u;
}

// float -> bf16 bits, round-to-nearest-even (input non-NaN)
__device__ __forceinline__ unsigned short f2bf(float f) {
    unsigned b = __float_as_uint(f);
    b = (b + 0x7fffu + ((b >> 16) & 1u)) >> 16;
    return (unsigned short)b;
}

__device__ __forceinline__ int refl(int g) {
    return g < 0 ? -g : (g >= IMG ? 2 * IMG - 2 - g : g);
}

// ---------------- stage 1: MFMA banded-conv pipeline (R3 structure, best-measured) ----------------
// modes: 0: h[v]  1: lpdf[v]=(-1)^v h[15-v]  2: |h[v]|  3: |h[15-v]|
__global__ __launch_bounds__(512, 6) void stego_stage1(
    const float* __restrict__ x, const float* __restrict__ hpdf,
    unsigned short* __restrict__ rho_out, float2* __restrict__ bmm)
{
    __shared__ __align__(16) _Float16 pool[POOLSZ];
    __shared__ float red[16];

    const int tid = threadIdx.x;
    const int lane = tid & 63;
    const int wid = __builtin_amdgcn_readfirstlane(tid >> 6);   // wave-uniform -> SALU
    const int n16 = lane & 15, quad = lane >> 4;

    // XCD-swizzled block decode: all 128 tiles of an image land on one XCD's L2
    const int blk = blockIdx.x;
    const int xcd = blk & 7;
    const int grp = blk >> 3;                 // 0..383
    const int img = xcd + ((grp >> 7) << 3);  // XCD c serves images {c, c+8, c+16}
    const int tl  = grp & 127;
    const int Oi = (tl >> 4) << 6;
    const int Oj = (tl & 15) << 5;
    const float* ximg = x + (size_t)img * (IMG * IMG);

    // ---- fragment-window table: ftab[(mode*41 + s)*8 + j] = c_mode[s + j - 16] ----
    for (int e = tid; e < 1312; e += 512) {
        const int mode = e / 328;
        const int rem  = e - mode * 328;
        const int tap  = (rem >> 3) + (rem & 7) - 16;      // s + j - 16
        float v = 0.f;
        if (tap >= 0 && tap <= 15) {
            int idx = (mode == 0 || mode == 2) ? tap : 15 - tap;
            float c = hpdf[idx];
            if (mode == 1 && (tap & 1)) c = -c;
            if (mode >= 2) c = fabsf(c);
            v = c;
        }
        pool[SA_FT + e] = (_Float16)v;
    }

    // ---- load X as fp16: rows Oi-15..Oi+78 (94 rows), cols Oj-16..Oj+47 (64 cols),
    //      rows 94..95 zeroed. Interior path: 3 aligned float4 loads / thread. ----
    {
        const int cg = tid & 15, row0 = tid >> 4;    // 16 col-quads x 32 rows, 3 steps
        const int c0 = Oj - 16 + 4 * cg;
        _Float16* dst = pool + SA_X + row0 * XST + 4 * cg;
        if (Oi >= 15 && Oi <= 433 && Oj >= 16 && Oj <= 464) {
            const float* src = ximg + (size_t)(Oi - 15 + row0) * IMG + c0;
            #pragma unroll
            for (int k = 0; k < 3; ++k) {
                const int row = row0 + (k << 5);
                uint2 pv = make_uint2(0u, 0u);
                if (row < 94) {
                    float4 xv = *(const float4*)(src + (size_t)(k << 5) * IMG);
                    pv.x = pkrtz(xv.x, xv.y);
                    pv.y = pkrtz(xv.z, xv.w);
                }
                *(uint2*)(dst + (size_t)(k << 5) * XST) = pv;
            }
        } else {
            const int gj0 = refl(c0),     gj1 = refl(c0 + 1);
            const int gj2 = refl(c0 + 2), gj3 = refl(c0 + 3);
            #pragma unroll
            for (int k = 0; k < 3; ++k) {
                const int row = row0 + (k << 5);
                uint2 pv = make_uint2(0u, 0u);
                if (row < 94) {
                    const float* rsrc = ximg + (size_t)refl(Oi - 15 + row) * IMG;
                    pv.x = pkrtz(rsrc[gj0], rsrc[gj1]);
                    pv.y = pkrtz(rsrc[gj2], rsrc[gj3]);
                }
                *(uint2*)(dst + (size_t)(k << 5) * XST) = pv;
            }
        }
    }
    __syncthreads();

    // ---- band fragments: one aligned ds_read_b128 per fragment.
    // band[4]: UNSHIFTED  B[k][n] = c[k-n]    (phases B, C, D)
    // bandA[2]: SHIFTED   B[k][n] = c[k-n-1]  (phase A only; X starts at Oj-16)
    v8h band[4], bandA[2];
    {
        const int sA = 16 + quad * 8 - n16;   // in [1,40]
        #pragma unroll
        for (int m = 0; m < 4; ++m)
            band[m] = load8(pool + SA_FT + (m * 41 + sA) * 8);
        #pragma unroll
        for (int m = 0; m < 2; ++m)
            bandA[m] = load8(pool + SA_FT + (m * 41 + sA - 1) * 8);
    }

    // ---- phase A: hconv X -> T_L', T_H' (18 tiles, shared A-frag, 2 MFMA each) ----
    for (int u = wid; u < 18; u += 8) {
        int mt = u % 6, nt = u / 6;
        int m0 = mt * 16, n0 = nt * 16;
        v8h a = load8(pool + SA_X + (m0 + n16) * XST + n0 + quad * 8);
        v4f z = {0.f, 0.f, 0.f, 0.f};
        v4f cL = __builtin_amdgcn_mfma_f32_16x16x32_f16(a, bandA[1], z, 0, 0, 0);
        v4f cH = __builtin_amdgcn_mfma_f32_16x16x32_f16(a, bandA[0], z, 0, 0, 0);
        int off = (n0 + n16) * TST + m0 + quad * 4;   // T'[col][row..row+3]
        store4(pool + SA_TL + off, cL);
        store4(pool + SA_TH + off, cH);
    }
    __syncthreads();

    float rho[4] = {0.f, 0.f, 0.f, 0.f};
    const int fB[3] = {0, 1, 0};   // HL: a=H, LH: a=L, HH: a=H
    const int fC[3] = {2, 3, 3};   // b2 mode
    const int fD[3] = {3, 2, 3};   // a2 mode

    // ---- phase B (fused over filters): vconv T -> R_f = |.| (45 tiles) ----
    #pragma unroll
    for (int f = 0; f < 3; ++f) {
        const _Float16* Tsrc = pool + (f == 0 ? SA_TL : SA_TH);
        _Float16* Rf = pool + SA_R + f * RSZ;
        for (int u = wid; u < 15; u += 8) {
            int nt = u % 5, mt = u / 5;
            int i0 = nt * 16, c0 = mt * 16;
            v8h a = load8(Tsrc + (c0 + n16) * TST + i0 + quad * 8);
            v4f z = {0.f, 0.f, 0.f, 0.f};
            v4f acc = __builtin_amdgcn_mfma_f32_16x16x32_f16(a, band[fB[f]], z, 0, 0, 0);
            store4abs(Rf + (i0 + n16) * RST + c0 + quad * 4, acc);
        }
    }
    __syncthreads();

    // ---- phase C (fused): hconv R_f -> U'_f (30 tiles) ----
    #pragma unroll
    for (int f = 0; f < 3; ++f) {
        const _Float16* Rf = pool + SA_R + f * RSZ;
        _Float16* Uf = pool + SA_U + f * USZ;
        for (int u = wid; u < 10; u += 8) {
            int mt = u % 5, nt = u / 5;
            int i0 = mt * 16, j0 = nt * 16;
            v8h a = load8(Rf + (i0 + n16) * RST + j0 + quad * 8);
            v4f z = {0.f, 0.f, 0.f, 0.f};
            v4f acc = __builtin_amdgcn_mfma_f32_16x16x32_f16(a, band[fC[f]], z, 0, 0, 0);
            store4(Uf + (j0 + n16) * UST + i0 + quad * 4, acc);
        }
    }
    __syncthreads();

    // ---- phase D (fused): vconv U_f -> xi; rho += 1/xi (24 tiles, 3/wave) ----
    {
        const int i0 = (wid & 3) * 16, c0 = (wid >> 2) * 16;
        #pragma unroll
        for (int f = 0; f < 3; ++f) {
            const _Float16* Uf = pool + SA_U + f * USZ;
            v8h a = load8(Uf + (c0 + n16) * UST + i0 + quad * 8);
            v4f z = {0.f, 0.f, 0.f, 0.f};
            v4f acc = __builtin_amdgcn_mfma_f32_16x16x32_f16(a, band[fD[f]], z, 0, 0, 0);
            #pragma unroll
            for (int r = 0; r < 4; ++r) rho[r] += __builtin_amdgcn_rcpf(acc[r]);
        }
    }

    // ---- finalize: clamp/NaN, bf16 round, NATURAL-layout aligned uint2 stores;
    //      roll applied at stage2 read. Per-block min/max unchanged. ----
    const size_t rbase = (size_t)img * (IMG * IMG);
    const int i_nat = Oi + (wid & 3) * 16 + n16;
    const int jb = Oj + ((wid >> 2) << 4) + quad * 4;
    float lmin = 1e38f, lmax = 0.f;
    unsigned pk0, pk1;
    {
        unsigned short b[4];
        #pragma unroll
        for (int r = 0; r < 4; ++r) {
            float v = rho[r];
            v = isnan(v) ? 1e10f : fminf(v, 1e10f);
            b[r] = f2bf(v);
            float rq = __uint_as_float((unsigned)b[r] << 16);
            lmin = fminf(lmin, rq);
            lmax = fmaxf(lmax, rq);
        }
        pk0 = (unsigned)b[0] | ((unsigned)b[1] << 16);
        pk1 = (unsigned)b[2] | ((unsigned)b[3] << 16);
    }
    *(uint2*)(rho_out + rbase + ((size_t)i_nat << 9) + jb) = make_uint2(pk0, pk1);

    #pragma unroll
    for (int off = 32; off >= 1; off >>= 1) {
        lmin = fminf(lmin, __shfl_xor(lmin, off));
        lmax = fmaxf(lmax, __shfl_xor(lmax, off));
    }
    if ((tid & 63) == 0) { red[wid] = lmin; red[8 + wid] = lmax; }
    __syncthreads();
    if (tid == 0) {
        float m0 = red[0], m1 = red[8];
        #pragma unroll
        for (int k = 1; k < 8; ++k) { m0 = fminf(m0, red[k]); m1 = fmaxf(m1, red[8 + k]); }
        bmm[(img << 7) + tl] = make_float2(m0, m1);
    }
}

// ---------------- stage 2: reduce minmax + rolled read + normalize + sigmoid + multiply ----------------
__global__ __launch_bounds__(256) void stego_stage2(
    const float* __restrict__ x, const unsigned short* __restrict__ rho,
    const float2* __restrict__ bmm, float* __restrict__ out)
{
    __shared__ float sred[8];
    const int tid = threadIdx.x;
    const int lane = tid & 63;

    // same XCD swizzle as stage1: read rho/x from the L2 that produced them
    const int blk = blockIdx.x;
    const int xcd = blk & 7, grp = blk >> 3;
    const int img = xcd + ((grp >> 7) << 3);
    const int chunk = grp & 127;                 // 128 blocks per image, 4 rows each
    const int t = (img << 15) + (chunk << 8) + tid;

    float lmn = 1e38f, lmx = 0.f;
    if (tid < 128) { float2 p = bmm[(img << 7) + tid]; lmn = p.x; lmx = p.y; }
    #pragma unroll
    for (int off = 32; off >= 1; off >>= 1) {
        lmn = fminf(lmn, __shfl_xor(lmn, off));
        lmx = fmaxf(lmx, __shfl_xor(lmx, off));
    }
    if (tid < 128 && (tid & 63) == 0) { sred[tid >> 6] = lmn; sred[4 + (tid >> 6)] = lmx; }
    __syncthreads();
    const float mn = fminf(sred[0], sred[1]);
    const float mx = fmaxf(sred[4], sred[5]);
    const float inv = __builtin_amdgcn_rcpf(mx - mn + 1e-8f);

    // rolled rho: rho_rolled[i][j] = rho_nat[(i-1)&511][(j-1)&511].
    // One wave == one 512-px row, so the j-1 shift is a single intra-wave shfl.
    const int i = (t >> 6) & 511;
    const int rrow = (i - 1) & 511;
    const size_t rb_off = ((size_t)img << 18) + ((size_t)rrow << 9) + ((size_t)lane << 3);
    uint4 rb = *(const uint4*)(rho + rb_off);
    unsigned ru[4] = {rb.x, rb.y, rb.z, rb.w};
    float f7 = __uint_as_float(ru[3] & 0xffff0000u);   // nat col 8*lane+7
    float r[8];
    r[0] = __shfl(f7, (lane + 63) & 63);               // prev lane's col 7 (wraps to col 511)
    r[1] = __uint_as_float(ru[0] << 16);
    r[2] = __uint_as_float(ru[0] & 0xffff0000u);
    r[3] = __uint_as_float(ru[1] << 16);
    r[4] = __uint_as_float(ru[1] & 0xffff0000u);
    r[5] = __uint_as_float(ru[2] << 16);
    r[6] = __uint_as_float(ru[2] & 0xffff0000u);
    r[7] = __uint_as_float(ru[3] << 16);

    const size_t base = (size_t)t << 3;
    const float* xrow = x + base;
    float4 xa = *(const float4*)xrow;
    float4 xb = *(const float4*)(xrow + 4);
    float xs[8] = {xa.x, xa.y, xa.z, xa.w, xb.x, xb.y, xb.z, xb.w};
    float os[8];
    #pragma unroll
    for (int k = 0; k < 8; ++k) {
        float rn = (r[k] - mn) * inv;
        os[k] = xs[k] * __builtin_amdgcn_rcpf(1.f + __expf(rn - 1.f));  // x * sigmoid(1-rn)
    }
    float* orow = out + base;
    *(float4*)orow       = make_float4(os[0], os[1], os[2], os[3]);
    *(float4*)(orow + 4) = make_float4(os[4], os[5], os[6], os[7]);
}

extern "C" void kernel_launch(void* const* d_in, const int* in_sizes, int n_in,
                              void* d_out, int out_size, void* d_ws, size_t ws_size,
                              hipStream_t stream) {
    const float* x    = (const float*)d_in[0];
    const float* hpdf = (const float*)d_in[1];
    float* out = (float*)d_out;

    unsigned short* rho = (unsigned short*)d_ws;                         // 24*512*512 bf16
    float2* bmm = (float2*)((char*)d_ws + (size_t)NIMG * IMG * IMG * 2); // 24*128 float2

    hipLaunchKernelGGL(stego_stage1, dim3(NIMG * 128), dim3(512), 0, stream,
                       x, hpdf, rho, bmm);
    hipLaunchKernelGGL(stego_stage2, dim3(NIMG * 128), dim3(256), 0, stream,
                       x, rho, bmm, out);
}